// Round 1
// baseline (519.560 us; speedup 1.0000x reference)
//
#include <hip/hip_runtime.h>
#include <hip/hip_bf16.h>

// PHM8Linear: out[t, j] = sum_k H[j,k] * x[t,k] + bias[j]
//   H[j,k] = sum_i A[i, j>>6, k>>6] * S[i, j&63, k&63]   (512x512, built in bf16)
//   M = 16*8192 = 131072, K = N = 512.
// Memory floor: 268 MB x-read + 268 MB out-write ~= 85 us @ 6.3 TB/s.
// GEMM: m97-style 128x128x32 tile, global_load_lds(16B) staging for both
// operands; A staged as fp32 (x is fp32 in HBM) and converted to bf16 at
// fragment load; XOR-row swizzle on A's 16B chunks to kill LDS bank conflicts.

#define MDIM (16 * 8192)
#define KD 512
#define ND 512
#define BM 128
#define BN 128
#define BK 32

typedef __attribute__((ext_vector_type(8))) short short8;
typedef __attribute__((ext_vector_type(4))) float f32x4;

__device__ __forceinline__ unsigned pack2_bf16(float x, float y) {
    union { __hip_bfloat162 h; unsigned u; } cv;
    cv.h = __float22bfloat162_rn(make_float2(x, y));
    return cv.u;
}

__device__ __forceinline__ short8 cvt_frag(f32x4 a, f32x4 b) {
    union { unsigned u[4]; short8 s; } r;
    r.u[0] = pack2_bf16(a.x, a.y);
    r.u[1] = pack2_bf16(a.z, a.w);
    r.u[2] = pack2_bf16(b.x, b.y);
    r.u[3] = pack2_bf16(b.z, b.w);
    return r.s;
}

__device__ __forceinline__ void async16(const void* g, void* l) {
    __builtin_amdgcn_global_load_lds(
        (const __attribute__((address_space(1))) unsigned*)g,
        (__attribute__((address_space(3))) unsigned*)l, 16, 0, 0);
}

// H[j*512 + k] = sum_i A[i*64 + (j>>6)*8 + (k>>6)] * S[i*4096 + (j&63)*64 + (k&63)]
__global__ void build_h(const float* __restrict__ A, const float* __restrict__ S,
                        __hip_bfloat16* __restrict__ H) {
    int idx = blockIdx.x * 256 + threadIdx.x;   // 0 .. 262143
    int j = idx >> 9, k = idx & 511;
    int a = j >> 6, b = j & 63, c = k >> 6, d = k & 63;
    float acc = 0.f;
#pragma unroll
    for (int i = 0; i < 8; ++i)
        acc += A[i * 64 + a * 8 + c] * S[i * 4096 + b * 64 + d];
    H[idx] = __float2bfloat16(acc);
}

__global__ __launch_bounds__(256)
void phm_gemm(const float* __restrict__ X, const __hip_bfloat16* __restrict__ Hm,
              const float* __restrict__ bias, float* __restrict__ out) {
    __shared__ float As[BM * BK];           // 16 KB fp32, 16B-chunk XOR-swizzled rows
    __shared__ __hip_bfloat16 Bs[BN * BK];  // 8 KB bf16, row-major

    const int tid = threadIdx.x;
    const int m0 = blockIdx.y * BM;
    const int n0 = blockIdx.x * BN;

    // ---- staging address precompute (LDS dst must be base + lane*16) ----
    // A: 1024 chunks of 16B; seg = q*256+tid; row=seg>>3, lds chunk col=seg&7,
    // global chunk col = (seg&7) ^ (row&7)  (XOR swizzle).
    const float* ag[4]; void* al[4];
#pragma unroll
    for (int q = 0; q < 4; ++q) {
        int seg = q * 256 + tid;
        int row = seg >> 3;
        int c16 = (seg & 7) ^ (row & 7);
        ag[q] = X + (size_t)(m0 + row) * KD + c16 * 4;
        al[q] = (char*)As + seg * 16;
    }
    // B: 512 chunks of 16B; row=seg>>2, col=seg&3 (no swizzle: 64-B rows are fine)
    const __hip_bfloat16* bg[2]; void* bl[2];
#pragma unroll
    for (int q = 0; q < 2; ++q) {
        int seg = q * 256 + tid;
        int row = seg >> 2;
        int c16 = seg & 3;
        bg[q] = Hm + (size_t)(n0 + row) * KD + c16 * 8;
        bl[q] = (char*)Bs + seg * 16;
    }

    const int wave = tid >> 6, lane = tid & 63;
    const int wm = (wave >> 1) * 64, wn = (wave & 1) * 64;
    const int fr = lane & 15;   // fragment row (A) / col (B)
    const int fs = lane >> 4;   // k-segment 0..3 (8 elems each)
    // A-fragment chunk slots after swizzle (constant per thread):
    const int ca = (2 * fs) ^ (fr & 7);  // holds k = fs*8 .. fs*8+3
    const int cb = ca ^ 1;               // holds k = fs*8+4 .. fs*8+7

    f32x4 acc[4][4];
#pragma unroll
    for (int i = 0; i < 4; ++i)
#pragma unroll
        for (int j = 0; j < 4; ++j) acc[i][j] = (f32x4)(0.f);

    for (int kt = 0; kt < KD / BK; ++kt) {
#pragma unroll
        for (int q = 0; q < 4; ++q) async16(ag[q] + kt * BK, al[q]);
#pragma unroll
        for (int q = 0; q < 2; ++q) async16(bg[q] + kt * BK, bl[q]);
        __syncthreads();   // compiler emits vmcnt(0) drain before barrier

        short8 bfr[4];
#pragma unroll
        for (int ni = 0; ni < 4; ++ni)
            bfr[ni] = *(const short8*)(Bs + (wn + ni * 16 + fr) * BK + fs * 8);

#pragma unroll
        for (int mi = 0; mi < 4; ++mi) {
            const float* rp = As + (wm + mi * 16 + fr) * BK;
            f32x4 a0 = *(const f32x4*)(rp + ca * 4);
            f32x4 a1 = *(const f32x4*)(rp + cb * 4);
            short8 afr = cvt_frag(a0, a1);
#pragma unroll
            for (int ni = 0; ni < 4; ++ni)
                acc[mi][ni] = __builtin_amdgcn_mfma_f32_16x16x32_bf16(
                    afr, bfr[ni], acc[mi][ni], 0, 0, 0);
        }
        __syncthreads();
    }

    // ---- epilogue: C/D layout col = lane&15, row = (lane>>4)*4 + reg ----
    const int cm = wm + fs * 4;
    const int cn0 = n0 + wn + fr;
#pragma unroll
    for (int mi = 0; mi < 4; ++mi) {
#pragma unroll
        for (int ni = 0; ni < 4; ++ni) {
            int col = cn0 + ni * 16;
            float bv = bias[col];
            float* op = out + (size_t)(m0 + cm + mi * 16) * ND + col;
#pragma unroll
            for (int r = 0; r < 4; ++r)
                op[(size_t)r * ND] = acc[mi][ni][r] + bv;
        }
    }
}

extern "C" void kernel_launch(void* const* d_in, const int* in_sizes, int n_in,
                              void* d_out, int out_size, void* d_ws, size_t ws_size,
                              hipStream_t stream) {
    const float* x    = (const float*)d_in[0];
    const float* A    = (const float*)d_in[1];
    const float* S    = (const float*)d_in[2];
    const float* bias = (const float*)d_in[3];
    float* out = (float*)d_out;
    __hip_bfloat16* H = (__hip_bfloat16*)d_ws;  // 512*512*2 = 512 KB scratch

    build_h<<<dim3(512 * 512 / 256), dim3(256), 0, stream>>>(A, S, H);
    phm_gemm<<<dim3(ND / BN, MDIM / BM), dim3(256), 0, stream>>>(x, H, bias, out);
}